// Round 1
// baseline (623.917 us; speedup 1.0000x reference)
//
#include <hip/hip_runtime.h>
#include <hip/hip_bf16.h>

// Problem constants
#define CC    1024   // embed dim
#define HH    16     // heads
#define SS    2      // signals
#define SD    32     // signal dim
#define HD    64     // head dim
#define NN    1024   // sequence length
#define BB    2      // batch
#define ROWS  (BB*NN)        // 2048 rows for projections
#define QSCALE 0.17677669529663687f  // 1/sqrt(32)

// ---------------------------------------------------------------------------
// Generic projection GEMM: Y[r][o] = dot(X[r,:], W[o,:]) + bias[o]
// mode 0: store q transposed  (B,H,S,N,sd), scaled by scl
// mode 1: store k transposed  (B,H,S,N,sd)
// mode 2: store v transposed  (B,H,N,hd)
// mode 3: plain store (B*N, C)
// ---------------------------------------------------------------------------
__global__ __launch_bounds__(256) void proj_kernel(
    const float* __restrict__ X, const float* __restrict__ W,
    const float* __restrict__ bias, float* __restrict__ out,
    int mode, float scl)
{
    __shared__ float Xs[16][65];
    __shared__ float Ws[16][65];

    const int tid = threadIdx.x;
    const int tx = tid & 15;        // 0..15 -> output col group
    const int ty = tid >> 4;        // 0..15 -> output row group
    const int row0 = blockIdx.y * 64;
    const int col0 = blockIdx.x * 64;

    float acc[4][4];
#pragma unroll
    for (int i = 0; i < 4; ++i)
#pragma unroll
        for (int j = 0; j < 4; ++j) acc[i][j] = 0.f;

    const int lr  = tid >> 2;        // 0..63 (row within tile)
    const int lc4 = (tid & 3) << 2;  // 0,4,8,12 (col within K-slab)

    for (int k0 = 0; k0 < CC; k0 += 16) {
        float4 xv = *(const float4*)&X[(size_t)(row0 + lr) * CC + k0 + lc4];
        float4 wv = *(const float4*)&W[(size_t)(col0 + lr) * CC + k0 + lc4];
        Xs[lc4 + 0][lr] = xv.x; Xs[lc4 + 1][lr] = xv.y;
        Xs[lc4 + 2][lr] = xv.z; Xs[lc4 + 3][lr] = xv.w;
        Ws[lc4 + 0][lr] = wv.x; Ws[lc4 + 1][lr] = wv.y;
        Ws[lc4 + 2][lr] = wv.z; Ws[lc4 + 3][lr] = wv.w;
        __syncthreads();
#pragma unroll
        for (int c = 0; c < 16; ++c) {
            float xr[4], wr[4];
#pragma unroll
            for (int i = 0; i < 4; ++i) xr[i] = Xs[c][ty * 4 + i];
#pragma unroll
            for (int j = 0; j < 4; ++j) wr[j] = Ws[c][tx * 4 + j];
#pragma unroll
            for (int i = 0; i < 4; ++i)
#pragma unroll
                for (int j = 0; j < 4; ++j) acc[i][j] += xr[i] * wr[j];
        }
        __syncthreads();
    }

#pragma unroll
    for (int i = 0; i < 4; ++i) {
        const int r = row0 + ty * 4 + i;      // 0..2047
        const int b = r >> 10;
        const int n = r & 1023;
#pragma unroll
        for (int j = 0; j < 4; ++j) {
            const int o = col0 + tx * 4 + j;  // 0..1023
            float y = (acc[i][j] + bias[o]) * scl;
            if (mode <= 1) {
                const int h = o >> 6, s = (o >> 5) & 1, ii = o & 31;
                out[((size_t)((b * HH + h) * SS + s) * NN + n) * SD + ii] = y;
            } else if (mode == 2) {
                const int h = o >> 6, d = o & 63;
                out[((size_t)(b * HH + h) * NN + n) * HD + d] = y;
            } else {
                out[(size_t)r * CC + o] = y;
            }
        }
    }
}

// ---------------------------------------------------------------------------
// Attention core. grid = (N/64, B*H). block = 256.
// Per block: 64 query rows of one (b,h); loops over both signals and all
// 16 key tiles of 64. score = 1 + x + x^2/2 with x = (q*scale).k
// ao[b][n][h*64+d] = 0.5*(numer0/den0 + numer1/den1)
// ---------------------------------------------------------------------------
__global__ __launch_bounds__(256) void attn_kernel(
    const float* __restrict__ qt, const float* __restrict__ kt,
    const float* __restrict__ vt, float* __restrict__ ao)
{
    __shared__ float Qs[2][64][33];
    __shared__ float Ks[64][33];
    __shared__ float Vs[64][64];
    __shared__ float Ss[64][65];

    const int tid = threadIdx.x;
    const int tx = tid & 15;
    const int ty = tid >> 4;
    const int bh = blockIdx.y;          // 0..31
    const int b  = bh >> 4;
    const int h  = bh & 15;
    const int n0 = blockIdx.x * 64;

    // stage Q for both signals (64 x 32 each)
#pragma unroll
    for (int s = 0; s < 2; ++s) {
        const float* qb = qt + ((size_t)((bh << 1) + s) * NN + n0) * SD;
#pragma unroll
        for (int p = 0; p < 2; ++p) {
            int idx = p * 256 + tid;       // 0..511 float4 slots
            int row = idx >> 3;
            int c4  = (idx & 7) << 2;
            float4 v = *(const float4*)&qb[row * SD + c4];
            Qs[s][row][c4 + 0] = v.x; Qs[s][row][c4 + 1] = v.y;
            Qs[s][row][c4 + 2] = v.z; Qs[s][row][c4 + 3] = v.w;
        }
    }

    float num[2][4][4];
    float den[2][4];
#pragma unroll
    for (int s = 0; s < 2; ++s) {
#pragma unroll
        for (int i = 0; i < 4; ++i) {
            den[s][i] = 0.f;
#pragma unroll
            for (int j = 0; j < 4; ++j) num[s][i][j] = 0.f;
        }
    }

    for (int m0 = 0; m0 < NN; m0 += 64) {
        // stage V tile (64x64) and K tile for s=0 (64x32)
        {
            const float* vb = vt + ((size_t)bh * NN + m0) * HD;
#pragma unroll
            for (int p = 0; p < 4; ++p) {
                int idx = p * 256 + tid;    // 0..1023
                int row = idx >> 4;
                int c4  = (idx & 15) << 2;
                *(float4*)&Vs[row][c4] = *(const float4*)&vb[row * HD + c4];
            }
            const float* kb = kt + ((size_t)((bh << 1) + 0) * NN + m0) * SD;
#pragma unroll
            for (int p = 0; p < 2; ++p) {
                int idx = p * 256 + tid;
                int row = idx >> 3;
                int c4  = (idx & 7) << 2;
                float4 v = *(const float4*)&kb[row * SD + c4];
                Ks[row][c4 + 0] = v.x; Ks[row][c4 + 1] = v.y;
                Ks[row][c4 + 2] = v.z; Ks[row][c4 + 3] = v.w;
            }
        }
        __syncthreads();

#pragma unroll
        for (int s = 0; s < 2; ++s) {
            // score tile: 4x4 per thread
            float sacc[4][4];
#pragma unroll
            for (int i = 0; i < 4; ++i)
#pragma unroll
                for (int j = 0; j < 4; ++j) sacc[i][j] = 0.f;
#pragma unroll
            for (int c = 0; c < SD; ++c) {
                float qr[4], kr[4];
#pragma unroll
                for (int i = 0; i < 4; ++i) qr[i] = Qs[s][ty * 4 + i][c];
#pragma unroll
                for (int j = 0; j < 4; ++j) kr[j] = Ks[tx * 4 + j][c];
#pragma unroll
                for (int i = 0; i < 4; ++i)
#pragma unroll
                    for (int j = 0; j < 4; ++j) sacc[i][j] += qr[i] * kr[j];
            }
#pragma unroll
            for (int i = 0; i < 4; ++i)
#pragma unroll
                for (int j = 0; j < 4; ++j) {
                    float x = sacc[i][j];
                    Ss[ty * 4 + i][tx * 4 + j] = 1.f + x * (1.f + 0.5f * x);
                }
            __syncthreads();

            // while Ss is being consumed, prefetch K for s=1 (only once)
            if (s == 0) {
                const float* kb = kt + ((size_t)((bh << 1) + 1) * NN + m0) * SD;
#pragma unroll
                for (int p = 0; p < 2; ++p) {
                    int idx = p * 256 + tid;
                    int row = idx >> 3;
                    int c4  = (idx & 7) << 2;
                    float4 v = *(const float4*)&kb[row * SD + c4];
                    Ks[row][c4 + 0] = v.x; Ks[row][c4 + 1] = v.y;
                    Ks[row][c4 + 2] = v.z; Ks[row][c4 + 3] = v.w;
                }
            }

            // PV accumulate
#pragma unroll 8
            for (int m = 0; m < 64; ++m) {
                float vv[4];
#pragma unroll
                for (int j = 0; j < 4; ++j) vv[j] = Vs[m][tx * 4 + j];
#pragma unroll
                for (int i = 0; i < 4; ++i) {
                    float sv = Ss[ty * 4 + i][m];
                    den[s][i] += sv;
#pragma unroll
                    for (int j = 0; j < 4; ++j) num[s][i][j] += sv * vv[j];
                }
            }
            __syncthreads();
        }
    }

    // epilogue: average signals, write (B,N,C)
#pragma unroll
    for (int i = 0; i < 4; ++i) {
        const int n = n0 + ty * 4 + i;
        float r0 = 1.f / (den[0][i] + 1e-6f);
        float r1 = 1.f / (den[1][i] + 1e-6f);
        float4 o4;
        float* po = &o4.x;
#pragma unroll
        for (int j = 0; j < 4; ++j)
            po[j] = 0.5f * (num[0][i][j] * r0 + num[1][i][j] * r1);
        *(float4*)&ao[((size_t)b * NN + n) * CC + h * HD + tx * 4] = o4;
    }
}

extern "C" void kernel_launch(void* const* d_in, const int* in_sizes, int n_in,
                              void* d_out, int out_size, void* d_ws, size_t ws_size,
                              hipStream_t stream) {
    const float* query = (const float*)d_in[0];
    const float* key_  = (const float*)d_in[1];
    const float* value = (const float*)d_in[2];
    const float* Wq = (const float*)d_in[3];
    const float* bq = (const float*)d_in[4];
    const float* Wk = (const float*)d_in[5];
    const float* bk = (const float*)d_in[6];
    const float* Wv = (const float*)d_in[7];
    const float* bv = (const float*)d_in[8];
    const float* Wo = (const float*)d_in[9];
    const float* bo = (const float*)d_in[10];
    float* out = (float*)d_out;

    float* ws = (float*)d_ws;
    const size_t SEG = (size_t)1 << 21;   // 2M floats per buffer
    float* qt = ws;
    float* kt = ws + SEG;
    float* vt = ws + 2 * SEG;
    float* ao = ws + 3 * SEG;

    dim3 pgrid(CC / 64, ROWS / 64);
    dim3 blk(256);
    hipLaunchKernelGGL(proj_kernel, pgrid, blk, 0, stream, query, Wq, bq, qt, 0, QSCALE);
    hipLaunchKernelGGL(proj_kernel, pgrid, blk, 0, stream, key_,  Wk, bk, kt, 1, 1.0f);
    hipLaunchKernelGGL(proj_kernel, pgrid, blk, 0, stream, value, Wv, bv, vt, 2, 1.0f);

    dim3 agrid(NN / 64, BB * HH);
    hipLaunchKernelGGL(attn_kernel, agrid, blk, 0, stream, qt, kt, vt, ao);

    hipLaunchKernelGGL(proj_kernel, pgrid, blk, 0, stream, ao, Wo, bo, out, 3, 1.0f);
}

// Round 2
// 164.507 us; speedup vs baseline: 3.7926x; 3.7926x over previous
//
#include <hip/hip_runtime.h>
#include <hip/hip_bf16.h>

#define CC 1024
#define NN 1024
#define BB 2
#define HH 16
#define QSCALE 0.17677669529663687f  // 1/sqrt(32)

typedef short bf16x8 __attribute__((ext_vector_type(8)));
typedef float f32x4  __attribute__((ext_vector_type(4)));

__device__ __forceinline__ f32x4 mfma16(bf16x8 a, bf16x8 b, f32x4 c) {
    return __builtin_amdgcn_mfma_f32_16x16x32_bf16(a, b, c, 0, 0, 0);
}
__device__ __forceinline__ short f2bf(float x) {
    __hip_bfloat16 h = __float2bfloat16(x);
    return *reinterpret_cast<short*>(&h);
}
__device__ __forceinline__ float bf2f(short s) {
    __hip_bfloat16 h;
    *reinterpret_cast<short*>(&h) = s;
    return __bfloat162float(h);
}

// ---------------------------------------------------------------------------
// Projection GEMM via MFMA.  Y[r][o] = dot(X[r,:], W[o,:]) + bias[o], scaled.
// Tile: BM=64 x BN=128, BK=32, 4 waves (2x2), per-wave 32x64 (2x4 frags).
// SPLIT=1: 3-term split-bf16 (near-fp32 accuracy) for the Wo projection.
// mode 0: q -> bf16 [b][h][s][n][32] (scaled)      mode 1: k -> same, unscaled
// mode 2: v -> bf16 [b][h][d][m] (transposed)      mode 3: fp32 [r][o]
// ---------------------------------------------------------------------------
template <int SPLIT>
__global__ __launch_bounds__(256) void proj_mfma(
    const float* __restrict__ X, const float* __restrict__ W,
    const float* __restrict__ bias, void* __restrict__ outp,
    int mode, float scl)
{
    __shared__ __align__(16) short Ah[64][32];
    __shared__ __align__(16) short Al[64][32];
    __shared__ __align__(16) short Bh[128][32];
    __shared__ __align__(16) short Bl[128][32];

    const int tid  = threadIdx.x;
    const int lane = tid & 63;
    const int wave = tid >> 6;
    const int wr = wave >> 1, wc = wave & 1;
    const int l16 = lane & 15, lk = lane >> 4;
    const int row0 = blockIdx.y * 64;
    const int col0 = blockIdx.x * 128;

    f32x4 acc[2][4];
#pragma unroll
    for (int m = 0; m < 2; ++m)
#pragma unroll
        for (int n = 0; n < 4; ++n) acc[m][n] = (f32x4){0.f, 0.f, 0.f, 0.f};

    const int sr = tid >> 3;        // 0..31
    const int sc = (tid & 7) << 2;  // 0..28

    for (int k0 = 0; k0 < CC; k0 += 32) {
        // stage X (64x32 fp32 -> bf16 hi/lo)
#pragma unroll
        for (int p = 0; p < 2; ++p) {
            float4 xv = *(const float4*)&X[(size_t)(row0 + sr + 32 * p) * CC + k0 + sc];
            float v[4] = {xv.x, xv.y, xv.z, xv.w};
#pragma unroll
            for (int j = 0; j < 4; ++j) {
                short h = f2bf(v[j]);
                Ah[sr + 32 * p][sc + j] = h;
                if (SPLIT) Al[sr + 32 * p][sc + j] = f2bf(v[j] - bf2f(h));
            }
        }
        // stage W (128x32)
#pragma unroll
        for (int p = 0; p < 4; ++p) {
            float4 wv = *(const float4*)&W[(size_t)(col0 + sr + 32 * p) * CC + k0 + sc];
            float v[4] = {wv.x, wv.y, wv.z, wv.w};
#pragma unroll
            for (int j = 0; j < 4; ++j) {
                short h = f2bf(v[j]);
                Bh[sr + 32 * p][sc + j] = h;
                if (SPLIT) Bl[sr + 32 * p][sc + j] = f2bf(v[j] - bf2f(h));
            }
        }
        __syncthreads();

        bf16x8 ah[2], al[2], bh[4], bl[4];
#pragma unroll
        for (int m = 0; m < 2; ++m) {
            ah[m] = *(const bf16x8*)&Ah[wr * 32 + m * 16 + l16][lk * 8];
            if (SPLIT) al[m] = *(const bf16x8*)&Al[wr * 32 + m * 16 + l16][lk * 8];
        }
#pragma unroll
        for (int n = 0; n < 4; ++n) {
            bh[n] = *(const bf16x8*)&Bh[wc * 64 + n * 16 + l16][lk * 8];
            if (SPLIT) bl[n] = *(const bf16x8*)&Bl[wc * 64 + n * 16 + l16][lk * 8];
        }
#pragma unroll
        for (int m = 0; m < 2; ++m)
#pragma unroll
            for (int n = 0; n < 4; ++n) {
                acc[m][n] = mfma16(ah[m], bh[n], acc[m][n]);
                if (SPLIT) {
                    acc[m][n] = mfma16(ah[m], bl[n], acc[m][n]);
                    acc[m][n] = mfma16(al[m], bh[n], acc[m][n]);
                }
            }
        __syncthreads();
    }

    // epilogue: C/D layout col = lane&15, row = (lane>>4)*4 + reg
#pragma unroll
    for (int m = 0; m < 2; ++m)
#pragma unroll
        for (int q = 0; q < 4; ++q) {
            const int r = row0 + wr * 32 + m * 16 + lk * 4 + q;
            const int b = r >> 10, n = r & 1023;
#pragma unroll
            for (int nf = 0; nf < 4; ++nf) {
                const int o = col0 + wc * 64 + nf * 16 + l16;
                float y = (acc[m][nf][q] + bias[o]) * scl;
                if (mode <= 1) {
                    const int h = o >> 6, s = (o >> 5) & 1, ii = o & 31;
                    ((short*)outp)[(((size_t)((b * HH + h) * 2 + s)) * NN + n) * 32 + ii] = f2bf(y);
                } else if (mode == 2) {
                    const int h = o >> 6, d = o & 63;
                    ((short*)outp)[(((size_t)(b * HH + h)) * 64 + d) * NN + n] = f2bf(y);
                } else {
                    ((float*)outp)[(size_t)r * CC + o] = y;
                }
            }
        }
}

// ---------------------------------------------------------------------------
// Attention core via MFMA. grid=(N/64, B*H), 256 threads (4 waves).
// wave = (signal s = wave>>1, row-half hf = wave&1): 32 q-rows of one signal.
// Per KV block of 64: S = Q K^T (K=32, one MFMA per frag), P = 1+x+x^2/2
// -> bf16 Ps in LDS -> PV with V^T tiles + ones-row fragment for denominator.
// Output ao fp32 (B,N,C); signals combined through Os in LDS.
// ---------------------------------------------------------------------------
__global__ __launch_bounds__(256) void attn_mfma(
    const short* __restrict__ qt, const short* __restrict__ kt,
    const short* __restrict__ vtg, float* __restrict__ ao)
{
    __shared__ __align__(16) short Ks[2][64][32];   // 8 KB
    __shared__ __align__(16) short Vt[80][72];      // 11.25 KB (rows 64..79: ones/zeros)
    __shared__ __align__(16) short Ps[2][64][72];   // 18 KB
    __shared__ __align__(16) float Os[64][68];      // 17 KB

    const int tid  = threadIdx.x;
    const int lane = tid & 63;
    const int wave = tid >> 6;
    const int s  = wave >> 1;
    const int hf = wave & 1;
    const int l16 = lane & 15, lk = lane >> 4;
    const int bh = blockIdx.y;
    const int n0 = blockIdx.x * 64;

    // constant denominator rows of Vt: row 64 = 1.0, rows 65..79 = 0
    for (int i = tid; i < 16 * 64; i += 256) {
        int rr = 64 + (i >> 6), cc = i & 63;
        Vt[rr][cc] = (rr == 64) ? (short)0x3F80 : (short)0;
    }

    // Q fragments stay in registers for the whole kernel
    bf16x8 qf[2];
#pragma unroll
    for (int m = 0; m < 2; ++m)
        qf[m] = *(const bf16x8*)&qt[((size_t)(bh * 2 + s) * NN + n0 + hf * 32 + m * 16 + l16) * 32 + lk * 8];

    f32x4 accn[2][4], accd[2];
#pragma unroll
    for (int nf = 0; nf < 2; ++nf) {
        accd[nf] = (f32x4){0.f, 0.f, 0.f, 0.f};
#pragma unroll
        for (int df = 0; df < 4; ++df) accn[nf][df] = (f32x4){0.f, 0.f, 0.f, 0.f};
    }

    for (int m0 = 0; m0 < NN; m0 += 64) {
        // stage K (2 signals x 64x32) and V^T (64 d-rows x 64 m-cols)
#pragma unroll
        for (int p = 0; p < 2; ++p) {
            int idx = p * 256 + tid;
            int ss = idx >> 8, j = idx & 255;
            int r = j >> 2, c8 = (j & 3) * 8;
            *(uint4*)&Ks[ss][r][c8] =
                *(const uint4*)&kt[((size_t)(bh * 2 + ss) * NN + m0 + r) * 32 + c8];
            int d = idx >> 3, c8v = (idx & 7) * 8;
            *(uint4*)&Vt[d][c8v] =
                *(const uint4*)&vtg[((size_t)(bh * 64 + d)) * NN + m0 + c8v];
        }
        __syncthreads();

        // QK^T: 2 n-frags x 4 m-frags, K=32 in one MFMA each
        f32x4 sacc[2][4];
#pragma unroll
        for (int nf = 0; nf < 2; ++nf)
#pragma unroll
            for (int mf = 0; mf < 4; ++mf) sacc[nf][mf] = (f32x4){0.f, 0.f, 0.f, 0.f};
        bf16x8 kf[4];
#pragma unroll
        for (int mf = 0; mf < 4; ++mf)
            kf[mf] = *(const bf16x8*)&Ks[s][mf * 16 + l16][lk * 8];
#pragma unroll
        for (int nf = 0; nf < 2; ++nf)
#pragma unroll
            for (int mf = 0; mf < 4; ++mf)
                sacc[nf][mf] = mfma16(qf[nf], kf[mf], sacc[nf][mf]);

        // P = 1 + x + x^2/2  -> bf16 into Ps
#pragma unroll
        for (int nf = 0; nf < 2; ++nf)
#pragma unroll
            for (int mf = 0; mf < 4; ++mf)
#pragma unroll
                for (int q = 0; q < 4; ++q) {
                    float x = sacc[nf][mf][q];
                    Ps[s][hf * 32 + nf * 16 + lk * 4 + q][mf * 16 + l16] =
                        f2bf(1.f + x * (1.f + 0.5f * x));
                }
        __syncthreads();

        // PV (+ ones-row fragment accumulates the denominator)
        bf16x8 vf[2][4], vd[2];
#pragma unroll
        for (int kb = 0; kb < 2; ++kb) {
#pragma unroll
            for (int df = 0; df < 4; ++df)
                vf[kb][df] = *(const bf16x8*)&Vt[df * 16 + l16][kb * 32 + lk * 8];
            vd[kb] = *(const bf16x8*)&Vt[64 + l16][kb * 32 + lk * 8];
        }
#pragma unroll
        for (int nf = 0; nf < 2; ++nf)
#pragma unroll
            for (int kb = 0; kb < 2; ++kb) {
                bf16x8 pf = *(const bf16x8*)&Ps[s][hf * 32 + nf * 16 + l16][kb * 32 + lk * 8];
#pragma unroll
                for (int df = 0; df < 4; ++df)
                    accn[nf][df] = mfma16(pf, vf[kb][df], accn[nf][df]);
                accd[nf] = mfma16(pf, vd[kb], accd[nf]);
            }
        __syncthreads();
    }

    // epilogue: den broadcast (valid at l16==0 of each 16-lane group), combine signals
    float inv[2][4];
#pragma unroll
    for (int nf = 0; nf < 2; ++nf)
#pragma unroll
        for (int q = 0; q < 4; ++q) {
            float dv = __shfl(accd[nf][q], lane & 48, 64);
            inv[nf][q] = 0.5f / (dv + 1e-6f);
        }

    if (s == 0) {
#pragma unroll
        for (int nf = 0; nf < 2; ++nf)
#pragma unroll
            for (int q = 0; q < 4; ++q) {
                int n = hf * 32 + nf * 16 + lk * 4 + q;
#pragma unroll
                for (int df = 0; df < 4; ++df)
                    Os[n][df * 16 + l16] = accn[nf][df][q] * inv[nf][q];
            }
    }
    __syncthreads();
    if (s == 1) {
        const int b = bh >> 4, h = bh & 15;
#pragma unroll
        for (int nf = 0; nf < 2; ++nf)
#pragma unroll
            for (int q = 0; q < 4; ++q) {
                int n = hf * 32 + nf * 16 + lk * 4 + q;
#pragma unroll
                for (int df = 0; df < 4; ++df) {
                    int d = df * 16 + l16;
                    ao[((size_t)b * NN + n0 + n) * CC + h * 64 + d] =
                        Os[n][d] + accn[nf][df][q] * inv[nf][q];
                }
            }
    }
}

extern "C" void kernel_launch(void* const* d_in, const int* in_sizes, int n_in,
                              void* d_out, int out_size, void* d_ws, size_t ws_size,
                              hipStream_t stream) {
    const float* query = (const float*)d_in[0];
    const float* key_  = (const float*)d_in[1];
    const float* value = (const float*)d_in[2];
    const float* Wq = (const float*)d_in[3];
    const float* bq = (const float*)d_in[4];
    const float* Wk = (const float*)d_in[5];
    const float* bk = (const float*)d_in[6];
    const float* Wv = (const float*)d_in[7];
    const float* bv = (const float*)d_in[8];
    const float* Wo = (const float*)d_in[9];
    const float* bo = (const float*)d_in[10];
    float* out = (float*)d_out;

    short* qt = (short*)d_ws;                 // 4 MB  [b][h][s][n][32] bf16
    short* kt = qt + ((size_t)1 << 21);       // 4 MB  [b][h][s][m][32] bf16
    short* vt = kt + ((size_t)1 << 21);       // 4 MB  [b][h][d][m]     bf16
    float* ao = (float*)(vt + ((size_t)1 << 21));  // 8 MB fp32 (B,N,C)

    dim3 blk(256);
    dim3 pgrid(CC / 128, (BB * NN) / 64);     // 8 x 32 = 256 blocks

    hipLaunchKernelGGL((proj_mfma<0>), pgrid, blk, 0, stream, query, Wq, bq, (void*)qt, 0, QSCALE);
    hipLaunchKernelGGL((proj_mfma<0>), pgrid, blk, 0, stream, key_,  Wk, bk, (void*)kt, 1, 1.0f);
    hipLaunchKernelGGL((proj_mfma<0>), pgrid, blk, 0, stream, value, Wv, bv, (void*)vt, 2, 1.0f);

    dim3 agrid(NN / 64, BB * HH);             // 16 x 32 = 512 blocks
    hipLaunchKernelGGL(attn_mfma, agrid, blk, 0, stream, qt, kt, vt, ao);

    hipLaunchKernelGGL((proj_mfma<1>), pgrid, blk, 0, stream, ao, Wo, bo, (void*)out, 3, 1.0f);
}

// Round 3
// 123.358 us; speedup vs baseline: 5.0578x; 1.3336x over previous
//
#include <hip/hip_runtime.h>
#include <hip/hip_bf16.h>

#define CC 1024
#define NN 1024
#define BB 2
#define HH 16
#define QSCALE 0.17677669529663687f  // 1/sqrt(32)

typedef short bf16x8 __attribute__((ext_vector_type(8)));
typedef float f32x4  __attribute__((ext_vector_type(4)));

__device__ __forceinline__ f32x4 mfma16(bf16x8 a, bf16x8 b, f32x4 c) {
    return __builtin_amdgcn_mfma_f32_16x16x32_bf16(a, b, c, 0, 0, 0);
}
__device__ __forceinline__ short f2bf(float x) {
    __hip_bfloat16 h = __float2bfloat16(x);
    return *reinterpret_cast<short*>(&h);
}
__device__ __forceinline__ float bf2f(short s) {
    __hip_bfloat16 h;
    *reinterpret_cast<short*>(&h) = s;
    return __bfloat162float(h);
}

// ---------------------------------------------------------------------------
// Fused QKV projection. grid (8 colblk, 16 rowblk, 3 proj), 256 thr.
// Tile 128x128, BK=32, 4 waves (2x2), per-wave 64x64 (4x4 frags).
// Register-prefetch staging: load K-slab k+1 into regs while MFMA'ing slab k.
// z=0: q -> bf16 [b][h][s][n][32] scaled   z=1: k -> same unscaled
// z=2: v -> bf16 [b][h][d][m] via LDS transpose (coalesced stores)
// ---------------------------------------------------------------------------
__global__ __launch_bounds__(256) void qkv_proj(
    const float* __restrict__ xq, const float* __restrict__ xk, const float* __restrict__ xv,
    const float* __restrict__ wq, const float* __restrict__ wk, const float* __restrict__ wv,
    const float* __restrict__ bq, const float* __restrict__ bk, const float* __restrict__ bv,
    short* __restrict__ qt, short* __restrict__ kt, short* __restrict__ vt)
{
    __shared__ short LD[17408];                       // 34816 B
    short (*A)[40]  = (short(*)[40])LD;               // 128 x 40 (pad: 2-way banks)
    short (*Bt)[40] = (short(*)[40])(LD + 128 * 40);  // 128 x 40
    short (*T)[136] = (short(*)[136])LD;              // mode-2 transpose (reuse)

    const int tid  = threadIdx.x;
    const int lane = tid & 63, wave = tid >> 6;
    const int wr = wave >> 1, wc = wave & 1;
    const int l16 = lane & 15, lk = lane >> 4;
    const int z    = blockIdx.z;
    const int col0 = blockIdx.x * 128;
    const int row0 = blockIdx.y * 128;

    const float* X    = (z == 0) ? xq : (z == 1) ? xk : xv;
    const float* W    = (z == 0) ? wq : (z == 1) ? wk : wv;
    const float* bias = (z == 0) ? bq : (z == 1) ? bk : bv;

    const int str = tid >> 3;          // 0..31
    const int stc = (tid & 7) << 2;    // 0,4,..,28

    float4 pa[4], pb[4];
#pragma unroll
    for (int p = 0; p < 4; ++p) {
        pa[p] = *(const float4*)&X[(size_t)(row0 + p * 32 + str) * CC + stc];
        pb[p] = *(const float4*)&W[(size_t)(col0 + p * 32 + str) * CC + stc];
    }

    f32x4 acc[4][4];
#pragma unroll
    for (int i = 0; i < 4; ++i)
#pragma unroll
        for (int j = 0; j < 4; ++j) acc[i][j] = (f32x4){0.f, 0.f, 0.f, 0.f};

    for (int k0 = 0; k0 < CC; k0 += 32) {
#pragma unroll
        for (int p = 0; p < 4; ++p) {
            ushort4 ua = { (unsigned short)f2bf(pa[p].x), (unsigned short)f2bf(pa[p].y),
                           (unsigned short)f2bf(pa[p].z), (unsigned short)f2bf(pa[p].w) };
            *(ushort4*)&A[p * 32 + str][stc] = ua;
            ushort4 ub = { (unsigned short)f2bf(pb[p].x), (unsigned short)f2bf(pb[p].y),
                           (unsigned short)f2bf(pb[p].z), (unsigned short)f2bf(pb[p].w) };
            *(ushort4*)&Bt[p * 32 + str][stc] = ub;
        }
        if (k0 + 32 < CC) {
#pragma unroll
            for (int p = 0; p < 4; ++p) {
                pa[p] = *(const float4*)&X[(size_t)(row0 + p * 32 + str) * CC + k0 + 32 + stc];
                pb[p] = *(const float4*)&W[(size_t)(col0 + p * 32 + str) * CC + k0 + 32 + stc];
            }
        }
        __syncthreads();
        bf16x8 af[4], bw[4];
#pragma unroll
        for (int i = 0; i < 4; ++i) {
            af[i] = *(const bf16x8*)&A[wr * 64 + i * 16 + l16][lk * 8];
            bw[i] = *(const bf16x8*)&Bt[wc * 64 + i * 16 + l16][lk * 8];
        }
#pragma unroll
        for (int mi = 0; mi < 4; ++mi)
#pragma unroll
            for (int nf = 0; nf < 4; ++nf)
                acc[mi][nf] = mfma16(af[mi], bw[nf], acc[mi][nf]);
        __syncthreads();
    }

    if (z <= 1) {
        short* outp = (z == 0) ? qt : kt;
        const float scl = (z == 0) ? QSCALE : 1.f;
#pragma unroll
        for (int mi = 0; mi < 4; ++mi)
#pragma unroll
            for (int q = 0; q < 4; ++q) {
                const int r = row0 + wr * 64 + mi * 16 + lk * 4 + q;
                const int b = r >> 10, n = r & 1023;
#pragma unroll
                for (int nf = 0; nf < 4; ++nf) {
                    const int o = col0 + wc * 64 + nf * 16 + l16;
                    const int h = o >> 6, s = (o >> 5) & 1, ii = o & 31;
                    float y = (acc[mi][nf][q] + bias[o]) * scl;
                    outp[(((size_t)((b * HH + h) * 2 + s)) << 15) + n * 32 + ii] = f2bf(y);
                }
            }
    } else {
        // transpose through LDS: T[col-in-block][row-in-block]
#pragma unroll
        for (int mi = 0; mi < 4; ++mi)
#pragma unroll
            for (int nf = 0; nf < 4; ++nf)
#pragma unroll
                for (int q = 0; q < 4; ++q) {
                    const int c = wc * 64 + nf * 16 + l16;
                    const int r = wr * 64 + mi * 16 + lk * 4 + q;
                    T[c][r] = f2bf(acc[mi][nf][q] + bias[col0 + c]);
                }
        __syncthreads();
        const int b  = row0 >> 10, n0 = row0 & 1023;
        const int c  = tid >> 1, half = tid & 1;
        const int oc = col0 + c, h = oc >> 6, d = oc & 63;
        const size_t base = (((size_t)(b * HH + h)) * 64 + d) * NN + n0 + half * 64;
#pragma unroll
        for (int u = 0; u < 8; ++u)
            *(uint4*)&vt[base + u * 8] = *(const uint4*)&T[c][half * 64 + u * 8];
    }
}

// ---------------------------------------------------------------------------
// Attention core via MFMA. grid=(16, 32), 256 thr (4 waves).
// wave = (signal s = wave>>1, row-half hf = wave&1): 32 q-rows of one signal.
// score = 1 + x + x^2/2; denominator via ones-row MFMA; K/V reg-prefetch.
// Writes ao as bf16 hi/lo pair (near-fp32) for the split Wo GEMM.
// ---------------------------------------------------------------------------
__global__ __launch_bounds__(256) void attn_mfma(
    const short* __restrict__ qt, const short* __restrict__ kt,
    const short* __restrict__ vtg, short* __restrict__ aoh, short* __restrict__ aol)
{
    __shared__ short Ks[2][64][40];   // padded: 2-way banks
    __shared__ short Vt[80][72];      // rows 64..79: ones/zeros for denom
    __shared__ short Ps[2][64][72];
    __shared__ float Os[64][68];

    const int tid  = threadIdx.x;
    const int lane = tid & 63;
    const int wave = tid >> 6;
    const int s  = wave >> 1;
    const int hf = wave & 1;
    const int l16 = lane & 15, lk = lane >> 4;
    const int bh = blockIdx.y;
    const int n0 = blockIdx.x * 64;

    for (int i = tid; i < 16 * 64; i += 256) {
        int rr = 64 + (i >> 6), cc = i & 63;
        Vt[rr][cc] = (rr == 64) ? (short)0x3F80 : (short)0;
    }

    bf16x8 qf[2];
#pragma unroll
    for (int m = 0; m < 2; ++m)
        qf[m] = *(const bf16x8*)&qt[((size_t)(bh * 2 + s) * NN + n0 + hf * 32 + m * 16 + l16) * 32 + lk * 8];

    uint4 kpf[2], vpf[2];
#pragma unroll
    for (int p = 0; p < 2; ++p) {
        int idx = p * 256 + tid;
        int ss = idx >> 8, j = idx & 255, r = j >> 2, c8 = (j & 3) << 3;
        kpf[p] = *(const uint4*)&kt[((size_t)(bh * 2 + ss) * NN + r) * 32 + c8];
        int d = idx >> 3, c8v = (idx & 7) << 3;
        vpf[p] = *(const uint4*)&vtg[((size_t)(bh * 64 + d)) * NN + c8v];
    }

    f32x4 accn[2][4], accd[2];
#pragma unroll
    for (int nf = 0; nf < 2; ++nf) {
        accd[nf] = (f32x4){0.f, 0.f, 0.f, 0.f};
#pragma unroll
        for (int df = 0; df < 4; ++df) accn[nf][df] = (f32x4){0.f, 0.f, 0.f, 0.f};
    }

    for (int m0 = 0; m0 < NN; m0 += 64) {
        // commit prefetched K/V to LDS
#pragma unroll
        for (int p = 0; p < 2; ++p) {
            int idx = p * 256 + tid;
            int ss = idx >> 8, j = idx & 255, r = j >> 2, c8 = (j & 3) << 3;
            *(uint4*)&Ks[ss][r][c8] = kpf[p];
            int d = idx >> 3, c8v = (idx & 7) << 3;
            *(uint4*)&Vt[d][c8v] = vpf[p];
        }
        if (m0 + 64 < NN) {
#pragma unroll
            for (int p = 0; p < 2; ++p) {
                int idx = p * 256 + tid;
                int ss = idx >> 8, j = idx & 255, r = j >> 2, c8 = (j & 3) << 3;
                kpf[p] = *(const uint4*)&kt[((size_t)(bh * 2 + ss) * NN + m0 + 64 + r) * 32 + c8];
                int d = idx >> 3, c8v = (idx & 7) << 3;
                vpf[p] = *(const uint4*)&vtg[((size_t)(bh * 64 + d)) * NN + m0 + 64 + c8v];
            }
        }
        __syncthreads();

        // QK^T for own signal
        f32x4 sacc[2][4];
#pragma unroll
        for (int nf = 0; nf < 2; ++nf)
#pragma unroll
            for (int mf = 0; mf < 4; ++mf) sacc[nf][mf] = (f32x4){0.f, 0.f, 0.f, 0.f};
        bf16x8 kf[4];
#pragma unroll
        for (int mf = 0; mf < 4; ++mf)
            kf[mf] = *(const bf16x8*)&Ks[s][mf * 16 + l16][lk * 8];
#pragma unroll
        for (int nf = 0; nf < 2; ++nf)
#pragma unroll
            for (int mf = 0; mf < 4; ++mf)
                sacc[nf][mf] = mfma16(qf[nf], kf[mf], sacc[nf][mf]);

        // P = 1 + x + x^2/2 -> bf16 Ps
#pragma unroll
        for (int nf = 0; nf < 2; ++nf)
#pragma unroll
            for (int mf = 0; mf < 4; ++mf)
#pragma unroll
                for (int q = 0; q < 4; ++q) {
                    float x = sacc[nf][mf][q];
                    Ps[s][hf * 32 + nf * 16 + lk * 4 + q][mf * 16 + l16] =
                        f2bf(1.f + x * (1.f + 0.5f * x));
                }
        __syncthreads();

        // PV (+ ones-row for denominator)
        bf16x8 vf[2][4], vd[2];
#pragma unroll
        for (int kb = 0; kb < 2; ++kb) {
#pragma unroll
            for (int df = 0; df < 4; ++df)
                vf[kb][df] = *(const bf16x8*)&Vt[df * 16 + l16][kb * 32 + lk * 8];
            vd[kb] = *(const bf16x8*)&Vt[64 + l16][kb * 32 + lk * 8];
        }
#pragma unroll
        for (int nf = 0; nf < 2; ++nf)
#pragma unroll
            for (int kb = 0; kb < 2; ++kb) {
                bf16x8 pf = *(const bf16x8*)&Ps[s][hf * 32 + nf * 16 + l16][kb * 32 + lk * 8];
#pragma unroll
                for (int df = 0; df < 4; ++df)
                    accn[nf][df] = mfma16(pf, vf[kb][df], accn[nf][df]);
                accd[nf] = mfma16(pf, vd[kb], accd[nf]);
            }
        __syncthreads();
    }

    float inv[2][4];
#pragma unroll
    for (int nf = 0; nf < 2; ++nf)
#pragma unroll
        for (int q = 0; q < 4; ++q) {
            float dv = __shfl(accd[nf][q], lane & 48, 64);
            inv[nf][q] = 0.5f / (dv + 1e-6f);
        }

    if (s == 0) {
#pragma unroll
        for (int nf = 0; nf < 2; ++nf)
#pragma unroll
            for (int q = 0; q < 4; ++q) {
                int n = hf * 32 + nf * 16 + lk * 4 + q;
#pragma unroll
                for (int df = 0; df < 4; ++df)
                    Os[n][df * 16 + l16] = accn[nf][df][q] * inv[nf][q];
            }
    }
    __syncthreads();
    if (s == 1) {
        const int b = bh >> 4, h = bh & 15;
#pragma unroll
        for (int nf = 0; nf < 2; ++nf)
#pragma unroll
            for (int q = 0; q < 4; ++q) {
                int n = hf * 32 + nf * 16 + lk * 4 + q;
#pragma unroll
                for (int df = 0; df < 4; ++df) {
                    int d = df * 16 + l16;
                    float o = Os[n][d] + accn[nf][df][q] * inv[nf][q];
                    size_t addr = ((size_t)b * NN + n0 + n) * CC + h * 64 + d;
                    short hi = f2bf(o);
                    aoh[addr] = hi;
                    aol[addr] = f2bf(o - bf2f(hi));
                }
            }
    }
}

// ---------------------------------------------------------------------------
// Output projection, 3-term split-bf16 (AhWh + AhWl + AlWh ~ fp32 accuracy).
// grid (16 colblk, 32 rowblk) = 512 blocks, tile 64x64, BK=32, 4 waves (2x2).
// A operand (aoh/aol) already bf16 from attn; W converted hi/lo in staging.
// ---------------------------------------------------------------------------
__global__ __launch_bounds__(256) void wo_proj(
    const short* __restrict__ aoh, const short* __restrict__ aol,
    const float* __restrict__ Wo, const float* __restrict__ bo,
    float* __restrict__ outp)
{
    __shared__ short Ah[64][40], Al[64][40], Wh[64][40], Wl[64][40];

    const int tid  = threadIdx.x;
    const int lane = tid & 63, wave = tid >> 6;
    const int wr = wave >> 1, wc = wave & 1;
    const int l16 = lane & 15, lk = lane >> 4;
    const int col0 = blockIdx.x * 64;
    const int row0 = blockIdx.y * 64;

    const int ar  = tid >> 2, ac8 = (tid & 3) << 3;   // A: 1 uint4/tensor/thread
    const int wrr = tid >> 3, wc4 = (tid & 7) << 2;   // W: 2 float4/thread

    uint4 ph, pl;
    float4 pw[2];
    ph = *(const uint4*)&aoh[(size_t)(row0 + ar) * CC + ac8];
    pl = *(const uint4*)&aol[(size_t)(row0 + ar) * CC + ac8];
#pragma unroll
    for (int p = 0; p < 2; ++p)
        pw[p] = *(const float4*)&Wo[(size_t)(col0 + p * 32 + wrr) * CC + wc4];

    f32x4 acc[2][2];
#pragma unroll
    for (int i = 0; i < 2; ++i)
#pragma unroll
        for (int j = 0; j < 2; ++j) acc[i][j] = (f32x4){0.f, 0.f, 0.f, 0.f};

    for (int k0 = 0; k0 < CC; k0 += 32) {
        *(uint4*)&Ah[ar][ac8] = ph;
        *(uint4*)&Al[ar][ac8] = pl;
#pragma unroll
        for (int p = 0; p < 2; ++p) {
            float v[4] = {pw[p].x, pw[p].y, pw[p].z, pw[p].w};
            unsigned short hs[4], ls[4];
#pragma unroll
            for (int j = 0; j < 4; ++j) {
                short hv = f2bf(v[j]);
                hs[j] = (unsigned short)hv;
                ls[j] = (unsigned short)f2bf(v[j] - bf2f(hv));
            }
            *(ushort4*)&Wh[p * 32 + wrr][wc4] = (ushort4){hs[0], hs[1], hs[2], hs[3]};
            *(ushort4*)&Wl[p * 32 + wrr][wc4] = (ushort4){ls[0], ls[1], ls[2], ls[3]};
        }
        if (k0 + 32 < CC) {
            ph = *(const uint4*)&aoh[(size_t)(row0 + ar) * CC + k0 + 32 + ac8];
            pl = *(const uint4*)&aol[(size_t)(row0 + ar) * CC + k0 + 32 + ac8];
#pragma unroll
            for (int p = 0; p < 2; ++p)
                pw[p] = *(const float4*)&Wo[(size_t)(col0 + p * 32 + wrr) * CC + k0 + 32 + wc4];
        }
        __syncthreads();
        bf16x8 ah[2], al[2], wh[2], wl[2];
#pragma unroll
        for (int i = 0; i < 2; ++i) {
            ah[i] = *(const bf16x8*)&Ah[wr * 32 + i * 16 + l16][lk * 8];
            al[i] = *(const bf16x8*)&Al[wr * 32 + i * 16 + l16][lk * 8];
            wh[i] = *(const bf16x8*)&Wh[wc * 32 + i * 16 + l16][lk * 8];
            wl[i] = *(const bf16x8*)&Wl[wc * 32 + i * 16 + l16][lk * 8];
        }
#pragma unroll
        for (int mi = 0; mi < 2; ++mi)
#pragma unroll
            for (int nj = 0; nj < 2; ++nj) {
                acc[mi][nj] = mfma16(ah[mi], wh[nj], acc[mi][nj]);
                acc[mi][nj] = mfma16(ah[mi], wl[nj], acc[mi][nj]);
                acc[mi][nj] = mfma16(al[mi], wh[nj], acc[mi][nj]);
            }
        __syncthreads();
    }

#pragma unroll
    for (int mi = 0; mi < 2; ++mi)
#pragma unroll
        for (int q = 0; q < 4; ++q) {
            const int r = row0 + wr * 32 + mi * 16 + lk * 4 + q;
#pragma unroll
            for (int nj = 0; nj < 2; ++nj) {
                const int o = col0 + wc * 32 + nj * 16 + l16;
                outp[(size_t)r * CC + o] = acc[mi][nj][q] + bo[o];
            }
        }
}

extern "C" void kernel_launch(void* const* d_in, const int* in_sizes, int n_in,
                              void* d_out, int out_size, void* d_ws, size_t ws_size,
                              hipStream_t stream) {
    const float* query = (const float*)d_in[0];
    const float* key_  = (const float*)d_in[1];
    const float* value = (const float*)d_in[2];
    const float* Wq = (const float*)d_in[3];
    const float* bq = (const float*)d_in[4];
    const float* Wk = (const float*)d_in[5];
    const float* bk = (const float*)d_in[6];
    const float* Wv = (const float*)d_in[7];
    const float* bv = (const float*)d_in[8];
    const float* Wo = (const float*)d_in[9];
    const float* bo = (const float*)d_in[10];
    float* out = (float*)d_out;

    short* qt  = (short*)d_ws;                 // 4 MB  [b][h][s][n][32]
    short* kt  = qt  + ((size_t)1 << 21);      // 4 MB  [b][h][s][m][32]
    short* vt  = kt  + ((size_t)1 << 21);      // 4 MB  [b][h][d][m]
    short* aoh = vt  + ((size_t)1 << 21);      // 4 MB  attn out hi
    short* aol = aoh + ((size_t)1 << 21);      // 4 MB  attn out lo

    dim3 blk(256);
    qkv_proj<<<dim3(8, 16, 3), blk, 0, stream>>>(query, key_, value, Wq, Wk, Wv,
                                                 bq, bk, bv, qt, kt, vt);
    attn_mfma<<<dim3(16, 32), blk, 0, stream>>>(qt, kt, vt, aoh, aol);
    wo_proj<<<dim3(16, 32), blk, 0, stream>>>(aoh, aol, Wo, bo, out);
}

// Round 4
// 107.987 us; speedup vs baseline: 5.7777x; 1.1423x over previous
//
#include <hip/hip_runtime.h>
#include <hip/hip_bf16.h>

#define CC 1024
#define NN 1024
#define BB 2
#define HH 16
#define QSCALE 0.17677669529663687f  // 1/sqrt(32)

typedef short bf16x8 __attribute__((ext_vector_type(8)));
typedef float f32x4  __attribute__((ext_vector_type(4)));

__device__ __forceinline__ f32x4 mfma16(bf16x8 a, bf16x8 b, f32x4 c) {
    return __builtin_amdgcn_mfma_f32_16x16x32_bf16(a, b, c, 0, 0, 0);
}
__device__ __forceinline__ short f2bf(float x) {
    __hip_bfloat16 h = __float2bfloat16(x);
    return *reinterpret_cast<short*>(&h);
}
__device__ __forceinline__ float bf2f(short s) {
    __hip_bfloat16 h;
    *reinterpret_cast<short*>(&h) = s;
    return __bfloat162float(h);
}

// ---------------------------------------------------------------------------
// Fused QKV projection (unchanged from round 3). grid (8,16,3), 256 thr.
// ---------------------------------------------------------------------------
__global__ __launch_bounds__(256) void qkv_proj(
    const float* __restrict__ xq, const float* __restrict__ xk, const float* __restrict__ xv,
    const float* __restrict__ wq, const float* __restrict__ wk, const float* __restrict__ wv,
    const float* __restrict__ bq, const float* __restrict__ bk, const float* __restrict__ bv,
    short* __restrict__ qt, short* __restrict__ kt, short* __restrict__ vt)
{
    __shared__ short LD[17408];
    short (*A)[40]  = (short(*)[40])LD;
    short (*Bt)[40] = (short(*)[40])(LD + 128 * 40);
    short (*T)[136] = (short(*)[136])LD;

    const int tid  = threadIdx.x;
    const int lane = tid & 63, wave = tid >> 6;
    const int wr = wave >> 1, wc = wave & 1;
    const int l16 = lane & 15, lk = lane >> 4;
    const int z    = blockIdx.z;
    const int col0 = blockIdx.x * 128;
    const int row0 = blockIdx.y * 128;

    const float* X    = (z == 0) ? xq : (z == 1) ? xk : xv;
    const float* W    = (z == 0) ? wq : (z == 1) ? wk : wv;
    const float* bias = (z == 0) ? bq : (z == 1) ? bk : bv;

    const int str = tid >> 3;
    const int stc = (tid & 7) << 2;

    float4 pa[4], pb[4];
#pragma unroll
    for (int p = 0; p < 4; ++p) {
        pa[p] = *(const float4*)&X[(size_t)(row0 + p * 32 + str) * CC + stc];
        pb[p] = *(const float4*)&W[(size_t)(col0 + p * 32 + str) * CC + stc];
    }

    f32x4 acc[4][4];
#pragma unroll
    for (int i = 0; i < 4; ++i)
#pragma unroll
        for (int j = 0; j < 4; ++j) acc[i][j] = (f32x4){0.f, 0.f, 0.f, 0.f};

    for (int k0 = 0; k0 < CC; k0 += 32) {
#pragma unroll
        for (int p = 0; p < 4; ++p) {
            ushort4 ua = { (unsigned short)f2bf(pa[p].x), (unsigned short)f2bf(pa[p].y),
                           (unsigned short)f2bf(pa[p].z), (unsigned short)f2bf(pa[p].w) };
            *(ushort4*)&A[p * 32 + str][stc] = ua;
            ushort4 ub = { (unsigned short)f2bf(pb[p].x), (unsigned short)f2bf(pb[p].y),
                           (unsigned short)f2bf(pb[p].z), (unsigned short)f2bf(pb[p].w) };
            *(ushort4*)&Bt[p * 32 + str][stc] = ub;
        }
        if (k0 + 32 < CC) {
#pragma unroll
            for (int p = 0; p < 4; ++p) {
                pa[p] = *(const float4*)&X[(size_t)(row0 + p * 32 + str) * CC + k0 + 32 + stc];
                pb[p] = *(const float4*)&W[(size_t)(col0 + p * 32 + str) * CC + k0 + 32 + stc];
            }
        }
        __syncthreads();
        bf16x8 af[4], bw[4];
#pragma unroll
        for (int i = 0; i < 4; ++i) {
            af[i] = *(const bf16x8*)&A[wr * 64 + i * 16 + l16][lk * 8];
            bw[i] = *(const bf16x8*)&Bt[wc * 64 + i * 16 + l16][lk * 8];
        }
#pragma unroll
        for (int mi = 0; mi < 4; ++mi)
#pragma unroll
            for (int nf = 0; nf < 4; ++nf)
                acc[mi][nf] = mfma16(af[mi], bw[nf], acc[mi][nf]);
        __syncthreads();
    }

    if (z <= 1) {
        short* outp = (z == 0) ? qt : kt;
        const float scl = (z == 0) ? QSCALE : 1.f;
#pragma unroll
        for (int mi = 0; mi < 4; ++mi)
#pragma unroll
            for (int q = 0; q < 4; ++q) {
                const int r = row0 + wr * 64 + mi * 16 + lk * 4 + q;
                const int b = r >> 10, n = r & 1023;
#pragma unroll
                for (int nf = 0; nf < 4; ++nf) {
                    const int o = col0 + wc * 64 + nf * 16 + l16;
                    const int h = o >> 6, s = (o >> 5) & 1, ii = o & 31;
                    float y = (acc[mi][nf][q] + bias[o]) * scl;
                    outp[(((size_t)((b * HH + h) * 2 + s)) << 15) + n * 32 + ii] = f2bf(y);
                }
            }
    } else {
#pragma unroll
        for (int mi = 0; mi < 4; ++mi)
#pragma unroll
            for (int nf = 0; nf < 4; ++nf)
#pragma unroll
                for (int q = 0; q < 4; ++q) {
                    const int c = wc * 64 + nf * 16 + l16;
                    const int r = wr * 64 + mi * 16 + lk * 4 + q;
                    T[c][r] = f2bf(acc[mi][nf][q] + bias[col0 + c]);
                }
        __syncthreads();
        const int b  = row0 >> 10, n0 = row0 & 1023;
        const int c  = tid >> 1, half = tid & 1;
        const int oc = col0 + c, h = oc >> 6, d = oc & 63;
        const size_t base = (((size_t)(b * HH + h)) * 64 + d) * NN + n0 + half * 64;
#pragma unroll
        for (int u = 0; u < 8; ++u)
            *(uint4*)&vt[base + u * 8] = *(const uint4*)&T[c][half * 64 + u * 8];
    }
}

// ---------------------------------------------------------------------------
// Attention core, LDS-traffic-optimized. grid=(16, 32), 256 thr (4 waves).
// wave = (s = wave>>1, hf = wave&1): 32 q-rows (n0+hf*32..+31) of signal s.
// Swapped QK^T: st = mfma(K, Q) -> lane holds P[m = mf*16+lk*4+r][n = nf*16+l16]
//   -> m-consecutive pack -> 1 ds_write_b64 per (mf,nf) into per-wave Ps[n][m].
// Denominator: sum f32 P in registers, cross-lane reduce in epilogue.
// PV: A = Ps rows (b128), B = V^T frags. 24 MFMA / ~24 KB LDS per wave-step.
// ---------------------------------------------------------------------------
__global__ __launch_bounds__(256) void attn_mfma(
    const short* __restrict__ qt, const short* __restrict__ kt,
    const short* __restrict__ vtg, short* __restrict__ aoh, short* __restrict__ aol)
{
    __shared__ __align__(16) short LDS_[18944];           // 37,888 B
    short* KsB = LDS_;                                    // [2][64][40]
    short* VtB = LDS_ + 5120;                             // [64][72]
    short* PsB = LDS_ + 9728;                             // [4][32][72]
    float* OsB = (float*)PsB;                             // [64][68] (epilogue overlay)

#define KS(ss, r, c)  KsB[((ss) * 64 + (r)) * 40 + (c)]
#define VT(d, m)      VtB[(d) * 72 + (m)]
#define PS(w, n, m)   PsB[((w) * 32 + (n)) * 72 + (m)]
#define OS(n, d)      OsB[(n) * 68 + (d)]

    const int tid  = threadIdx.x;
    const int lane = tid & 63;
    const int wave = tid >> 6;
    const int s  = wave >> 1;
    const int hf = wave & 1;
    const int l16 = lane & 15, lk = lane >> 4;
    const int bh = blockIdx.y;
    const int n0 = blockIdx.x * 64;

    // Q fragments (A-layout content; used as MFMA B-operand = Q^T)
    bf16x8 qf[2];
#pragma unroll
    for (int nf = 0; nf < 2; ++nf)
        qf[nf] = *(const bf16x8*)&qt[((size_t)(bh * 2 + s) * NN + n0 + hf * 32 + nf * 16 + l16) * 32 + lk * 8];

    // prefetch first K/V tiles into registers
    uint4 kpf[2], vpf[2];
#pragma unroll
    for (int p = 0; p < 2; ++p) {
        int idx = p * 256 + tid;
        int ss = idx >> 8, j = idx & 255, r = j >> 2, c8 = (j & 3) << 3;
        kpf[p] = *(const uint4*)&kt[((size_t)(bh * 2 + ss) * NN + r) * 32 + c8];
        int d = idx >> 3, c8v = (idx & 7) << 3;
        vpf[p] = *(const uint4*)&vtg[((size_t)(bh * 64 + d)) * NN + c8v];
    }

    f32x4 accn[2][4];
#pragma unroll
    for (int nf = 0; nf < 2; ++nf)
#pragma unroll
        for (int df = 0; df < 4; ++df) accn[nf][df] = (f32x4){0.f, 0.f, 0.f, 0.f};
    float den[2] = {0.f, 0.f};

    for (int m0 = 0; m0 < NN; m0 += 64) {
        // commit prefetched K/V to LDS
#pragma unroll
        for (int p = 0; p < 2; ++p) {
            int idx = p * 256 + tid;
            int ss = idx >> 8, j = idx & 255, r = j >> 2, c8 = (j & 3) << 3;
            *(uint4*)&KS(ss, r, c8) = kpf[p];
            int d = idx >> 3, c8v = (idx & 7) << 3;
            *(uint4*)&VT(d, c8v) = vpf[p];
        }
        if (m0 + 64 < NN) {
#pragma unroll
            for (int p = 0; p < 2; ++p) {
                int idx = p * 256 + tid;
                int ss = idx >> 8, j = idx & 255, r = j >> 2, c8 = (j & 3) << 3;
                kpf[p] = *(const uint4*)&kt[((size_t)(bh * 2 + ss) * NN + m0 + 64 + r) * 32 + c8];
                int d = idx >> 3, c8v = (idx & 7) << 3;
                vpf[p] = *(const uint4*)&vtg[((size_t)(bh * 64 + d)) * NN + m0 + 64 + c8v];
            }
        }
        __syncthreads();

        // QK^T (swapped) + polynomial + packed P-write + register denominator
#pragma unroll
        for (int mf = 0; mf < 4; ++mf) {
            bf16x8 kf = *(const bf16x8*)&KS(s, mf * 16 + l16, lk * 8);
#pragma unroll
            for (int nf = 0; nf < 2; ++nf) {
                f32x4 st = mfma16(kf, qf[nf], (f32x4){0.f, 0.f, 0.f, 0.f});
                float p0 = 1.f + st[0] * (1.f + 0.5f * st[0]);
                float p1 = 1.f + st[1] * (1.f + 0.5f * st[1]);
                float p2 = 1.f + st[2] * (1.f + 0.5f * st[2]);
                float p3 = 1.f + st[3] * (1.f + 0.5f * st[3]);
                den[nf] += (p0 + p1) + (p2 + p3);
                short pk[4] = {f2bf(p0), f2bf(p1), f2bf(p2), f2bf(p3)};
                *(uint2*)&PS(wave, nf * 16 + l16, mf * 16 + lk * 4) = *(uint2*)pk;
            }
        }

        // PV (same-wave Ps dependency -> no barrier, compiler lgkmcnt orders)
#pragma unroll
        for (int kb = 0; kb < 2; ++kb) {
            bf16x8 vf[4];
#pragma unroll
            for (int df = 0; df < 4; ++df)
                vf[df] = *(const bf16x8*)&VT(df * 16 + l16, kb * 32 + lk * 8);
#pragma unroll
            for (int nf = 0; nf < 2; ++nf) {
                bf16x8 pf = *(const bf16x8*)&PS(wave, nf * 16 + l16, kb * 32 + lk * 8);
#pragma unroll
                for (int df = 0; df < 4; ++df)
                    accn[nf][df] = mfma16(pf, vf[df], accn[nf][df]);
            }
        }
        __syncthreads();
    }

    // full denominator: reduce over lk groups, then redistribute per q
    float invq[2][4];
#pragma unroll
    for (int nf = 0; nf < 2; ++nf) {
        float d = den[nf];
        d += __shfl_xor(d, 16, 64);
        d += __shfl_xor(d, 32, 64);   // d = den for n = nf*16 + l16, all lanes
#pragma unroll
        for (int q = 0; q < 4; ++q)
            invq[nf][q] = 0.5f / (__shfl(d, (lane & 48) + lk * 4 + q, 64) + 1e-6f);
    }

    if (s == 0) {
#pragma unroll
        for (int nf = 0; nf < 2; ++nf)
#pragma unroll
            for (int q = 0; q < 4; ++q)
#pragma unroll
                for (int df = 0; df < 4; ++df)
                    OS(hf * 32 + nf * 16 + lk * 4 + q, df * 16 + l16) =
                        accn[nf][df][q] * invq[nf][q];
    }
    __syncthreads();
    if (s == 1) {
        const int b = bh >> 4, h = bh & 15;
#pragma unroll
        for (int nf = 0; nf < 2; ++nf)
#pragma unroll
            for (int q = 0; q < 4; ++q) {
                const int n = hf * 32 + nf * 16 + lk * 4 + q;
#pragma unroll
                for (int df = 0; df < 4; ++df) {
                    const int d = df * 16 + l16;
                    float o = OS(n, d) + accn[nf][df][q] * invq[nf][q];
                    size_t addr = ((size_t)b * NN + n0 + n) * CC + h * 64 + d;
                    short hi = f2bf(o);
                    aoh[addr] = hi;
                    aol[addr] = f2bf(o - bf2f(hi));
                }
            }
    }
#undef KS
#undef VT
#undef PS
#undef OS
}

// ---------------------------------------------------------------------------
// Output projection, 3-term split-bf16 (unchanged from round 3).
// ---------------------------------------------------------------------------
__global__ __launch_bounds__(256) void wo_proj(
    const short* __restrict__ aoh, const short* __restrict__ aol,
    const float* __restrict__ Wo, const float* __restrict__ bo,
    float* __restrict__ outp)
{
    __shared__ short Ah[64][40], Al[64][40], Wh[64][40], Wl[64][40];

    const int tid  = threadIdx.x;
    const int lane = tid & 63, wave = tid >> 6;
    const int wr = wave >> 1, wc = wave & 1;
    const int l16 = lane & 15, lk = lane >> 4;
    const int col0 = blockIdx.x * 64;
    const int row0 = blockIdx.y * 64;

    const int ar  = tid >> 2, ac8 = (tid & 3) << 3;
    const int wrr = tid >> 3, wc4 = (tid & 7) << 2;

    uint4 ph, pl;
    float4 pw[2];
    ph = *(const uint4*)&aoh[(size_t)(row0 + ar) * CC + ac8];
    pl = *(const uint4*)&aol[(size_t)(row0 + ar) * CC + ac8];
#pragma unroll
    for (int p = 0; p < 2; ++p)
        pw[p] = *(const float4*)&Wo[(size_t)(col0 + p * 32 + wrr) * CC + wc4];

    f32x4 acc[2][2];
#pragma unroll
    for (int i = 0; i < 2; ++i)
#pragma unroll
        for (int j = 0; j < 2; ++j) acc[i][j] = (f32x4){0.f, 0.f, 0.f, 0.f};

    for (int k0 = 0; k0 < CC; k0 += 32) {
        *(uint4*)&Ah[ar][ac8] = ph;
        *(uint4*)&Al[ar][ac8] = pl;
#pragma unroll
        for (int p = 0; p < 2; ++p) {
            float v[4] = {pw[p].x, pw[p].y, pw[p].z, pw[p].w};
            unsigned short hs[4], ls[4];
#pragma unroll
            for (int j = 0; j < 4; ++j) {
                short hv = f2bf(v[j]);
                hs[j] = (unsigned short)hv;
                ls[j] = (unsigned short)f2bf(v[j] - bf2f(hv));
            }
            *(ushort4*)&Wh[p * 32 + wrr][wc4] = (ushort4){hs[0], hs[1], hs[2], hs[3]};
            *(ushort4*)&Wl[p * 32 + wrr][wc4] = (ushort4){ls[0], ls[1], ls[2], ls[3]};
        }
        if (k0 + 32 < CC) {
            ph = *(const uint4*)&aoh[(size_t)(row0 + ar) * CC + k0 + 32 + ac8];
            pl = *(const uint4*)&aol[(size_t)(row0 + ar) * CC + k0 + 32 + ac8];
#pragma unroll
            for (int p = 0; p < 2; ++p)
                pw[p] = *(const float4*)&Wo[(size_t)(col0 + p * 32 + wrr) * CC + k0 + 32 + wc4];
        }
        __syncthreads();
        bf16x8 ah[2], al[2], wh[2], wl[2];
#pragma unroll
        for (int i = 0; i < 2; ++i) {
            ah[i] = *(const bf16x8*)&Ah[wr * 32 + i * 16 + l16][lk * 8];
            al[i] = *(const bf16x8*)&Al[wr * 32 + i * 16 + l16][lk * 8];
            wh[i] = *(const bf16x8*)&Wh[wc * 32 + i * 16 + l16][lk * 8];
            wl[i] = *(const bf16x8*)&Wl[wc * 32 + i * 16 + l16][lk * 8];
        }
#pragma unroll
        for (int mi = 0; mi < 2; ++mi)
#pragma unroll
            for (int nj = 0; nj < 2; ++nj) {
                acc[mi][nj] = mfma16(ah[mi], wh[nj], acc[mi][nj]);
                acc[mi][nj] = mfma16(ah[mi], wl[nj], acc[mi][nj]);
                acc[mi][nj] = mfma16(al[mi], wh[nj], acc[mi][nj]);
            }
        __syncthreads();
    }

#pragma unroll
    for (int mi = 0; mi < 2; ++mi)
#pragma unroll
        for (int q = 0; q < 4; ++q) {
            const int r = row0 + wr * 32 + mi * 16 + lk * 4 + q;
#pragma unroll
            for (int nj = 0; nj < 2; ++nj) {
                const int o = col0 + wc * 32 + nj * 16 + l16;
                outp[(size_t)r * CC + o] = acc[mi][nj][q] + bo[o];
            }
        }
}

extern "C" void kernel_launch(void* const* d_in, const int* in_sizes, int n_in,
                              void* d_out, int out_size, void* d_ws, size_t ws_size,
                              hipStream_t stream) {
    const float* query = (const float*)d_in[0];
    const float* key_  = (const float*)d_in[1];
    const float* value = (const float*)d_in[2];
    const float* Wq = (const float*)d_in[3];
    const float* bq = (const float*)d_in[4];
    const float* Wk = (const float*)d_in[5];
    const float* bk = (const float*)d_in[6];
    const float* Wv = (const float*)d_in[7];
    const float* bv = (const float*)d_in[8];
    const float* Wo = (const float*)d_in[9];
    const float* bo = (const float*)d_in[10];
    float* out = (float*)d_out;

    short* qt  = (short*)d_ws;                 // 4 MB  [b][h][s][n][32]
    short* kt  = qt  + ((size_t)1 << 21);      // 4 MB  [b][h][s][m][32]
    short* vt  = kt  + ((size_t)1 << 21);      // 4 MB  [b][h][d][m]
    short* aoh = vt  + ((size_t)1 << 21);      // 4 MB  attn out hi
    short* aol = aoh + ((size_t)1 << 21);      // 4 MB  attn out lo

    dim3 blk(256);
    qkv_proj<<<dim3(8, 16, 3), blk, 0, stream>>>(query, key_, value, Wq, Wk, Wv,
                                                 bq, bk, bv, qt, kt, vt);
    attn_mfma<<<dim3(16, 32), blk, 0, stream>>>(qt, kt, vt, aoh, aol);
    wo_proj<<<dim3(16, 32), blk, 0, stream>>>(aoh, aol, Wo, bo, out);
}